// Round 4
// baseline (8777.754 us; speedup 1.0000x reference)
//
#include <hip/hip_runtime.h>
#include <hip/hip_bf16.h>

// Problem constants
#define BB 32
#define SS 512
#define DD 256
#define HH 256
#define GG 1024          // 4*H
#define MM (SS*BB)       // 16384 rows, m = s*32 + b
#define NSENT 16
#define TT 12
#define TAG_START 10
#define TAG_STOP 11

typedef unsigned long long u64;
typedef unsigned int u32;

__device__ __forceinline__ float sigm(float x) { return 1.f / (1.f + expf(-x)); }

// ---------------- embed gather: X1[m][d] = embed[inputs[b][s]][d], m = s*32+b
__global__ void embed_kernel(const int* __restrict__ toks, const float* __restrict__ emb,
                             float* __restrict__ X1) {
  int m = blockIdx.x;
  int s = m >> 5, b = m & 31;
  int tok = toks[b * SS + s];
  ((float4*)(X1 + (size_t)m * DD))[threadIdx.x] =
      ((const float4*)(emb + (size_t)tok * DD))[threadIdx.x];
}

// ---------------- fp32 NT GEMM: C[M,N] = A[M,K] @ W[N,K]^T + bias, 64x64 tile
// LDS leading dim padded 64->68: staging writes 2-way max (free), b128 reads conflict-free.
__launch_bounds__(256)
__global__ void gemm_nt(const float* __restrict__ A, const float* __restrict__ W,
                        const float* __restrict__ bias, float* __restrict__ C,
                        int K, int ldC) {
  __shared__ float As[16 * 68];
  __shared__ float Ws[16 * 68];
  const int tid = threadIdx.x;
  const int n0 = blockIdx.x * 64, m0 = blockIdx.y * 64;
  const int row = tid >> 2, q = tid & 3;
  const int tn = tid & 15, tm = tid >> 4;
  float acc[4][4] = {};
  for (int kk = 0; kk < K; kk += 16) {
    float4 a = *(const float4*)(A + (size_t)(m0 + row) * K + kk + q * 4);
    float4 w = *(const float4*)(W + (size_t)(n0 + row) * K + kk + q * 4);
    As[(q * 4 + 0) * 68 + row] = a.x; As[(q * 4 + 1) * 68 + row] = a.y;
    As[(q * 4 + 2) * 68 + row] = a.z; As[(q * 4 + 3) * 68 + row] = a.w;
    Ws[(q * 4 + 0) * 68 + row] = w.x; Ws[(q * 4 + 1) * 68 + row] = w.y;
    Ws[(q * 4 + 2) * 68 + row] = w.z; Ws[(q * 4 + 3) * 68 + row] = w.w;
    __syncthreads();
#pragma unroll
    for (int kl = 0; kl < 16; ++kl) {
      const float4 av = *(const float4*)(As + kl * 68 + tm * 4);
      const float4 wv = *(const float4*)(Ws + kl * 68 + tn * 4);
      const float am[4] = {av.x, av.y, av.z, av.w};
      const float wm[4] = {wv.x, wv.y, wv.z, wv.w};
#pragma unroll
      for (int i = 0; i < 4; ++i)
#pragma unroll
        for (int j = 0; j < 4; ++j) acc[i][j] = fmaf(am[i], wm[j], acc[i][j]);
    }
    __syncthreads();
  }
  float4 bz = make_float4(0.f, 0.f, 0.f, 0.f);
  if (bias) bz = *(const float4*)(bias + n0 + tn * 4);
#pragma unroll
  for (int i = 0; i < 4; ++i) {
    float4 o = make_float4(acc[i][0] + bz.x, acc[i][1] + bz.y,
                           acc[i][2] + bz.z, acc[i][3] + bz.w);
    *(float4*)(C + (size_t)(m0 + tm * 4 + i) * ldC + n0 + tn * 4) = o;
  }
}

// ---------------- whh repack with XOR-swizzle for conflict-free b128 reads.
// out[((dir*8+sl)*128 + r)*256 + ((k4 ^ (r&63))*4 + ki)] = whh[dir][g][k]
//   r = gate*32 + j, g = gate*256 + sl*32 + j, k = k4*4 + ki
__global__ void prep_whh(const float* __restrict__ whh, float* __restrict__ out) {
  int idx = blockIdx.x * 256 + threadIdx.x;        // 2*8*128*256 = 524288
  int pos = idx & 255;
  int r = (idx >> 8) & 127;
  int sl = (idx >> 15) & 7;
  int dir = idx >> 18;
  int ki = pos & 3;
  int k4 = (pos >> 2) ^ (r & 63);
  int k = k4 * 4 + ki;
  int g = (r >> 5) * 256 + sl * 32 + (r & 31);
  out[idx] = whh[(size_t)(dir * GG + g) * HH + k];
}

// ---------------- LSTM recurrence (one layer, both dirs), 2 interleaved chains/wg.
// grid = 128: bid = (d*8+p) + 16*sl.  wg handles slice sl (32 units), dir d,
// chains A=(bg 2p: batches 4p,4p+1), B=(bg 2p+1: batches 4p+2,4p+3).
// Sync protocol: self-flagging 64-bit words (tag<<32 | float bits), relaxed
// agent-scope 8B atomics (atomic at device coherence point). Double-buffered by
// t-parity. Consumer polls the data directly — no flags, no fences. Chain A's
// words for step t+1 are prefetched during chain B's compute (and vice versa),
// hiding the L3 round trip under ~1us of compute.
__launch_bounds__(128)
__global__ void rec_kernel(const float* __restrict__ Xp, const float* __restrict__ whh_p,
                           float* __restrict__ hist, u64* __restrict__ hx) {
  __shared__ float whh_lds[32768];   // [r*256 + swz(k)], 128KB
  __shared__ float h_lds[512];       // [c*256 + k]
  __shared__ float g_lds[256];       // [r*2 + c]
  __shared__ float c_lds[2][64];     // [chain][c*32 + j]
  const int tid = threadIdx.x;
  const int bid = blockIdx.x;
  const int sl = bid >> 4;
  const int d = (bid & 15) >> 3;
  const int p = bid & 7;
  const int g0 = 2 * p, g1 = 2 * p + 1;
  const int r = tid;                 // row 0..127 (gate*32+j)
  const int swz = (r & 63);
  const float* wp = whh_p + (size_t)(d * 8 + sl) * 32768;
  for (int i = tid * 4; i < 32768; i += 512)
    *(float4*)&whh_lds[i] = *(const float4*)&wp[i];
  if (tid < 64) { c_lds[0][tid] = 0.f; c_lds[1][tid] = 0.f; }
  const float* XpD = Xp + (size_t)d * MM * GG;
  const int gcol = (r >> 5) * 256 + sl * 32 + (r & 31);
  const int jj = tid & 31, cc = tid >> 5;        // epilogue mapping (tid<64)
  // consumer pointers: hx[slot][d][g][c*256+k], word index = tid*4+q
  u64* hxA[2] = { hx + ((size_t)(0 * 2 + d) * 16 + g0) * 512 + tid * 4,
                  hx + ((size_t)(1 * 2 + d) * 16 + g0) * 512 + tid * 4 };
  u64* hxB[2] = { hx + ((size_t)(0 * 2 + d) * 16 + g1) * 512 + tid * 4,
                  hx + ((size_t)(1 * 2 + d) * 16 + g1) * 512 + tid * 4 };
  u64 pA0, pA1, pA2, pA3, pB0, pB1, pB2, pB3;
  // prime chain-A prefetch for t=0 (slot 0, tag 0 = memset state)
  {
    u64* c0 = hxA[0];
    pA0 = __hip_atomic_load(c0 + 0, __ATOMIC_RELAXED, __HIP_MEMORY_SCOPE_AGENT);
    pA1 = __hip_atomic_load(c0 + 1, __ATOMIC_RELAXED, __HIP_MEMORY_SCOPE_AGENT);
    pA2 = __hip_atomic_load(c0 + 2, __ATOMIC_RELAXED, __HIP_MEMORY_SCOPE_AGENT);
    pA3 = __hip_atomic_load(c0 + 3, __ATOMIC_RELAXED, __HIP_MEMORY_SCOPE_AGENT);
  }
  __syncthreads();   // whh_lds / c_lds ready
  for (int t = 0; t < SS; ++t) {
    const int s = d ? (SS - 1 - t) : t;
    const u32 expt = (u32)t;
    // xp loads for this superstep (A used after ~0.7us, B after ~1.8us)
    const float xpA0 = XpD[(size_t)(s * BB + 4 * p + 0) * GG + gcol];
    const float xpA1 = XpD[(size_t)(s * BB + 4 * p + 1) * GG + gcol];
    const float xpB0 = XpD[(size_t)(s * BB + 4 * p + 2) * GG + gcol];
    const float xpB1 = XpD[(size_t)(s * BB + 4 * p + 3) * GG + gcol];
    // ---- phase A ----
    {
      u64* c0 = hxA[t & 1];
      while ((u32)(pA0 >> 32) != expt || (u32)(pA1 >> 32) != expt ||
             (u32)(pA2 >> 32) != expt || (u32)(pA3 >> 32) != expt) {
        __builtin_amdgcn_s_sleep(1);
        pA0 = __hip_atomic_load(c0 + 0, __ATOMIC_RELAXED, __HIP_MEMORY_SCOPE_AGENT);
        pA1 = __hip_atomic_load(c0 + 1, __ATOMIC_RELAXED, __HIP_MEMORY_SCOPE_AGENT);
        pA2 = __hip_atomic_load(c0 + 2, __ATOMIC_RELAXED, __HIP_MEMORY_SCOPE_AGENT);
        pA3 = __hip_atomic_load(c0 + 3, __ATOMIC_RELAXED, __HIP_MEMORY_SCOPE_AGENT);
      }
    }
    *(float4*)&h_lds[tid * 4] = make_float4(
        __uint_as_float((u32)pA0), __uint_as_float((u32)pA1),
        __uint_as_float((u32)pA2), __uint_as_float((u32)pA3));
    __syncthreads();
    // issue B prefetch (consumed after A's compute, ~0.8us from now)
    {
      u64* c1 = hxB[t & 1];
      pB0 = __hip_atomic_load(c1 + 0, __ATOMIC_RELAXED, __HIP_MEMORY_SCOPE_AGENT);
      pB1 = __hip_atomic_load(c1 + 1, __ATOMIC_RELAXED, __HIP_MEMORY_SCOPE_AGENT);
      pB2 = __hip_atomic_load(c1 + 2, __ATOMIC_RELAXED, __HIP_MEMORY_SCOPE_AGENT);
      pB3 = __hip_atomic_load(c1 + 3, __ATOMIC_RELAXED, __HIP_MEMORY_SCOPE_AGENT);
    }
    {
      float acc0 = 0.f, acc1 = 0.f;
#pragma unroll 8
      for (int k4 = 0; k4 < 64; ++k4) {
        const float4 w = *(const float4*)&whh_lds[r * 256 + ((k4 ^ swz) << 2)];
        const float4 h0 = *(const float4*)&h_lds[k4 * 4];
        const float4 h1 = *(const float4*)&h_lds[256 + k4 * 4];
        acc0 = fmaf(w.x, h0.x, acc0); acc0 = fmaf(w.y, h0.y, acc0);
        acc0 = fmaf(w.z, h0.z, acc0); acc0 = fmaf(w.w, h0.w, acc0);
        acc1 = fmaf(w.x, h1.x, acc1); acc1 = fmaf(w.y, h1.y, acc1);
        acc1 = fmaf(w.z, h1.z, acc1); acc1 = fmaf(w.w, h1.w, acc1);
      }
      *(float2*)&g_lds[r * 2] = make_float2(acc0 + xpA0, acc1 + xpA1);
    }
    __syncthreads();
    if (tid < 64) {   // epilogue A (wave 0 only)
      const float iv = g_lds[(jj) * 2 + cc];
      const float fv = g_lds[(32 + jj) * 2 + cc];
      const float gv = g_lds[(64 + jj) * 2 + cc];
      const float ov = g_lds[(96 + jj) * 2 + cc];
      const float cs = sigm(fv) * c_lds[0][cc * 32 + jj] + sigm(iv) * tanhf(gv);
      c_lds[0][cc * 32 + jj] = cs;
      const float hn = sigm(ov) * tanhf(cs);
      u64 w = ((u64)(u32)(t + 1) << 32) | (u64)__float_as_uint(hn);
      __hip_atomic_store(
          hx + ((size_t)(((t + 1) & 1) * 2 + d) * 16 + g0) * 512 + cc * 256 + sl * 32 + jj,
          w, __ATOMIC_RELAXED, __HIP_MEMORY_SCOPE_AGENT);
      hist[(size_t)(s * BB + 4 * p + cc) * 512 + d * 256 + sl * 32 + jj] = hn;
    }
    // ---- phase B ----
    {
      u64* c1 = hxB[t & 1];
      while ((u32)(pB0 >> 32) != expt || (u32)(pB1 >> 32) != expt ||
             (u32)(pB2 >> 32) != expt || (u32)(pB3 >> 32) != expt) {
        __builtin_amdgcn_s_sleep(1);
        pB0 = __hip_atomic_load(c1 + 0, __ATOMIC_RELAXED, __HIP_MEMORY_SCOPE_AGENT);
        pB1 = __hip_atomic_load(c1 + 1, __ATOMIC_RELAXED, __HIP_MEMORY_SCOPE_AGENT);
        pB2 = __hip_atomic_load(c1 + 2, __ATOMIC_RELAXED, __HIP_MEMORY_SCOPE_AGENT);
        pB3 = __hip_atomic_load(c1 + 3, __ATOMIC_RELAXED, __HIP_MEMORY_SCOPE_AGENT);
      }
    }
    *(float4*)&h_lds[tid * 4] = make_float4(
        __uint_as_float((u32)pB0), __uint_as_float((u32)pB1),
        __uint_as_float((u32)pB2), __uint_as_float((u32)pB3));
    __syncthreads();
    // issue next-superstep A prefetch (consumed after B's compute)
    {
      u64* c0 = hxA[(t + 1) & 1];
      pA0 = __hip_atomic_load(c0 + 0, __ATOMIC_RELAXED, __HIP_MEMORY_SCOPE_AGENT);
      pA1 = __hip_atomic_load(c0 + 1, __ATOMIC_RELAXED, __HIP_MEMORY_SCOPE_AGENT);
      pA2 = __hip_atomic_load(c0 + 2, __ATOMIC_RELAXED, __HIP_MEMORY_SCOPE_AGENT);
      pA3 = __hip_atomic_load(c0 + 3, __ATOMIC_RELAXED, __HIP_MEMORY_SCOPE_AGENT);
    }
    {
      float acc0 = 0.f, acc1 = 0.f;
#pragma unroll 8
      for (int k4 = 0; k4 < 64; ++k4) {
        const float4 w = *(const float4*)&whh_lds[r * 256 + ((k4 ^ swz) << 2)];
        const float4 h0 = *(const float4*)&h_lds[k4 * 4];
        const float4 h1 = *(const float4*)&h_lds[256 + k4 * 4];
        acc0 = fmaf(w.x, h0.x, acc0); acc0 = fmaf(w.y, h0.y, acc0);
        acc0 = fmaf(w.z, h0.z, acc0); acc0 = fmaf(w.w, h0.w, acc0);
        acc1 = fmaf(w.x, h1.x, acc1); acc1 = fmaf(w.y, h1.y, acc1);
        acc1 = fmaf(w.z, h1.z, acc1); acc1 = fmaf(w.w, h1.w, acc1);
      }
      __syncthreads();   // epilogue-A g_lds reads done before overwrite
      *(float2*)&g_lds[r * 2] = make_float2(acc0 + xpB0, acc1 + xpB1);
    }
    __syncthreads();
    if (tid < 64) {   // epilogue B
      const float iv = g_lds[(jj) * 2 + cc];
      const float fv = g_lds[(32 + jj) * 2 + cc];
      const float gv = g_lds[(64 + jj) * 2 + cc];
      const float ov = g_lds[(96 + jj) * 2 + cc];
      const float cs = sigm(fv) * c_lds[1][cc * 32 + jj] + sigm(iv) * tanhf(gv);
      c_lds[1][cc * 32 + jj] = cs;
      const float hn = sigm(ov) * tanhf(cs);
      u64 w = ((u64)(u32)(t + 1) << 32) | (u64)__float_as_uint(hn);
      __hip_atomic_store(
          hx + ((size_t)(((t + 1) & 1) * 2 + d) * 16 + g1) * 512 + cc * 256 + sl * 32 + jj,
          w, __ATOMIC_RELAXED, __HIP_MEMORY_SCOPE_AGENT);
      hist[(size_t)(s * BB + 4 * p + 2 + cc) * 512 + d * 256 + sl * 32 + jj] = hn;
    }
    __syncthreads();   // h_lds reuse next superstep
  }
}

// ---------------- attention: scores over NS=16 sentence embs, softmax, g; writes comb[512:1024]
__global__ void att_kernel(float* __restrict__ comb, const float* __restrict__ sent) {
  __shared__ float sl[NSENT * 512];   // 32 KB
  __shared__ float wxr[512];
  __shared__ float parts[256];
  __shared__ float aw[NSENT];
  __shared__ float red0;
  const int tid = threadIdx.x;
  const int b = blockIdx.y;
  const int s0 = blockIdx.x * 32;
  for (int i = tid; i < NSENT * 512; i += 256) sl[i] = sent[(size_t)b * NSENT * 512 + i];
  __syncthreads();
  for (int si = 0; si < 32; ++si) {
    const int m = (s0 + si) * BB + b;
    float* crow = comb + (size_t)m * 1024;
    for (int i = tid; i < 512; i += 256) wxr[i] = crow[i];
    __syncthreads();
    const int n = tid >> 4, kp = tid & 15;
    float p = 0.f;
#pragma unroll 8
    for (int f = kp * 32; f < kp * 32 + 32; ++f) p = fmaf(wxr[f], sl[n * 512 + f], p);
    parts[tid] = p;
    __syncthreads();
    if (tid < NSENT) {
      float sc = 0.f;
      for (int qq = 0; qq < 16; ++qq) sc += parts[tid * 16 + qq];
      aw[tid] = sc;
    }
    __syncthreads();
    if (tid == 0) {
      float mx = aw[0];
      for (int qq = 1; qq < NSENT; ++qq) mx = fmaxf(mx, aw[qq]);
      float sm = 0.f;
      for (int qq = 0; qq < NSENT; ++qq) { float e = expf(aw[qq] - mx); aw[qq] = e; sm += e; }
      red0 = 1.f / sm;
    }
    __syncthreads();
    const float inv = red0;
    for (int f = tid; f < 512; f += 256) {
      float g = 0.f;
#pragma unroll
      for (int qq = 0; qq < NSENT; ++qq) g = fmaf(aw[qq], sl[qq * 512 + f], g);
      crow[512 + f] = g * inv;
    }
    __syncthreads();
  }
}

// ---------------- feats[m][t] = l2m[m][:] . h2t_w[t][:] + h2t_b[t]; wave per row
__global__ void feats_kernel(const float* __restrict__ l2m, const float* __restrict__ w,
                             const float* __restrict__ bias, float* __restrict__ feats) {
  const int wave = threadIdx.x >> 6, lane = threadIdx.x & 63;
  const int m = blockIdx.x * 4 + wave;
  const float* row = l2m + (size_t)m * 512;
  float rv[8];
#pragma unroll
  for (int i = 0; i < 8; ++i) rv[i] = row[lane + i * 64];
  for (int t = 0; t < TT; ++t) {
    const float* wr = w + t * 512;
    float p = 0.f;
#pragma unroll
    for (int i = 0; i < 8; ++i) p = fmaf(rv[i], wr[lane + i * 64], p);
#pragma unroll
    for (int off = 32; off; off >>= 1) p += __shfl_down(p, off);
    if (lane == 0) feats[(size_t)m * TT + t] = p + bias[t];
  }
}

// ---------------- viterbi per batch; 1 wave, whole DP in LDS
__global__ void viterbi_kernel(const float* __restrict__ feats, const float* __restrict__ trans,
                               int* __restrict__ out) {
  __shared__ float flds[SS * TT];
  __shared__ unsigned char bp[SS * TT];
  __shared__ float tr[TT * TT];
  __shared__ float fv[TT];
  __shared__ float tv[TT];
  __shared__ int pathS[SS];
  const int b = blockIdx.x, tid = threadIdx.x;
  for (int i = tid; i < SS * TT; i += 64) {
    int s = i / TT, t = i - s * TT;
    flds[i] = feats[(size_t)(s * BB + b) * TT + t];
  }
  for (int i = tid; i < TT * TT; i += 64) tr[i] = trans[i];
  if (tid < TT) fv[tid] = (tid == TAG_START) ? 0.f : -10000.f;
  __syncthreads();
  for (int s = 0; s < SS; ++s) {
    float nf = 0.f;
    if (tid < TT) {
      float mx = -1e30f;
      int bj = 0;
#pragma unroll
      for (int jj = 0; jj < TT; ++jj) {
        float v = fv[jj] + tr[tid * TT + jj];
        if (v > mx) { mx = v; bj = jj; }
      }
      nf = mx + flds[s * TT + tid];
      bp[s * TT + tid] = (unsigned char)bj;
    }
    __syncthreads();
    if (tid < TT) fv[tid] = nf;
    __syncthreads();
  }
  if (tid < TT) tv[tid] = fv[tid] + tr[TAG_STOP * TT + tid];
  __syncthreads();
  if (tid == 0) {
    int best = 0;
    float mx = tv[0];
    for (int jj = 1; jj < TT; ++jj)
      if (tv[jj] > mx) { mx = tv[jj]; best = jj; }
    pathS[SS - 1] = best;
    for (int s = SS - 1; s > 0; --s) { best = bp[s * TT + best]; pathS[s - 1] = best; }
  }
  __syncthreads();
  for (int s = tid; s < SS; s += 64) out[b * SS + s] = pathS[s];
}

// ---------------- workspace layout (bytes) — total ~240.4 MB < 256 MB ----------------
#define OFF_XP    ((size_t)0)               // 2*16384*1024*4 = 134217728
#define OFF_COMB  ((size_t)134217728)       // 16384*1024*4 = 67108864 (X1 and l2m alias here)
#define OFF_WORD  ((size_t)201326592)       // 16384*512*4  = 33554432
#define OFF_WT1   ((size_t)234881024)       // 2097152
#define OFF_WT2   ((size_t)236978176)       // 2097152
#define OFF_FEATS ((size_t)239075328)       // 786432
#define OFF_HX1   ((size_t)239861760)       // 262144  (2 slots * 2 dir * 16 g * 512 u64)
#define OFF_HX2   ((size_t)240123904)       // 262144

extern "C" void kernel_launch(void* const* d_in, const int* in_sizes, int n_in,
                              void* d_out, int out_size, void* d_ws, size_t ws_size,
                              hipStream_t stream) {
  const int* inputs  = (const int*)d_in[0];
  const float* sent  = (const float*)d_in[1];
  const float* emb   = (const float*)d_in[2];
  const float* l1wih = (const float*)d_in[3];
  const float* l1whh = (const float*)d_in[4];
  const float* l1b   = (const float*)d_in[5];
  const float* l2wih = (const float*)d_in[6];
  const float* l2whh = (const float*)d_in[7];
  const float* l2b   = (const float*)d_in[8];
  const float* attW  = (const float*)d_in[9];
  const float* h2tw  = (const float*)d_in[10];
  const float* h2tb  = (const float*)d_in[11];
  const float* trans = (const float*)d_in[12];
  int* out = (int*)d_out;
  char* ws = (char*)d_ws;

  float* Xp    = (float*)(ws + OFF_XP);
  float* comb  = (float*)(ws + OFF_COMB);
  float* word  = (float*)(ws + OFF_WORD);
  float* X1    = comb;   // X1 dead before comb is written (wx GEMM reads word only)
  float* l2m   = comb;   // comb dead before rec2 writes l2m
  float* wt1   = (float*)(ws + OFF_WT1);
  float* wt2   = (float*)(ws + OFF_WT2);
  float* feats = (float*)(ws + OFF_FEATS);
  u64* hx1     = (u64*)(ws + OFF_HX1);
  u64* hx2     = (u64*)(ws + OFF_HX2);

  // zero both tagged-h buffers (contiguous 512 KB): tag 0 == "h_{-1}=0 ready"
  hipMemsetAsync(ws + OFF_HX1, 0, 262144 * 2, stream);

  prep_whh<<<2048, 256, 0, stream>>>(l1whh, wt1);
  prep_whh<<<2048, 256, 0, stream>>>(l2whh, wt2);
  embed_kernel<<<MM, 64, 0, stream>>>(inputs, emb, X1);
  for (int d = 0; d < 2; ++d)
    gemm_nt<<<dim3(16, 256), 256, 0, stream>>>(X1, l1wih + (size_t)d * GG * DD,
                                               l1b + d * GG, Xp + (size_t)d * MM * GG,
                                               DD, GG);
  rec_kernel<<<128, 128, 0, stream>>>(Xp, wt1, word, hx1);
  gemm_nt<<<dim3(8, 256), 256, 0, stream>>>(word, attW, nullptr, comb, 512, 1024);
  att_kernel<<<dim3(16, 32), 256, 0, stream>>>(comb, sent);
  for (int d = 0; d < 2; ++d)
    gemm_nt<<<dim3(16, 256), 256, 0, stream>>>(comb, l2wih + (size_t)d * GG * GG,
                                               l2b + d * GG, Xp + (size_t)d * MM * GG,
                                               GG, GG);
  rec_kernel<<<128, 128, 0, stream>>>(Xp, wt2, l2m, hx2);
  feats_kernel<<<MM / 4, 256, 0, stream>>>(l2m, h2tw, h2tb, feats);
  viterbi_kernel<<<BB, 64, 0, stream>>>(feats, trans, out);
}

// Round 5
// 6120.572 us; speedup vs baseline: 1.4341x; 1.4341x over previous
//
#include <hip/hip_runtime.h>
#include <hip/hip_bf16.h>

// Problem constants
#define BB 32
#define SS 512
#define DD 256
#define HH 256
#define GG 1024          // 4*H
#define MM (SS*BB)       // 16384 rows, m = s*32 + b
#define NSENT 16
#define TT 12
#define TAG_START 10
#define TAG_STOP 11

typedef unsigned long long u64;
typedef unsigned int u32;

__device__ __forceinline__ float sigm(float x) { return 1.f / (1.f + expf(-x)); }

// ---------------- embed gather: X1[m][d] = embed[inputs[b][s]][d], m = s*32+b
__global__ void embed_kernel(const int* __restrict__ toks, const float* __restrict__ emb,
                             float* __restrict__ X1) {
  int m = blockIdx.x;
  int s = m >> 5, b = m & 31;
  int tok = toks[b * SS + s];
  ((float4*)(X1 + (size_t)m * DD))[threadIdx.x] =
      ((const float4*)(emb + (size_t)tok * DD))[threadIdx.x];
}

// ---------------- fp32 NT GEMM: C[M,N] = A[M,K] @ W[N,K]^T + bias, 64x64 tile
// LDS leading dim padded 64->68: staging writes 2-way max (free), b128 reads conflict-free.
__launch_bounds__(256)
__global__ void gemm_nt(const float* __restrict__ A, const float* __restrict__ W,
                        const float* __restrict__ bias, float* __restrict__ C,
                        int K, int ldC) {
  __shared__ float As[16 * 68];
  __shared__ float Ws[16 * 68];
  const int tid = threadIdx.x;
  const int n0 = blockIdx.x * 64, m0 = blockIdx.y * 64;
  const int row = tid >> 2, q = tid & 3;
  const int tn = tid & 15, tm = tid >> 4;
  float acc[4][4] = {};
  for (int kk = 0; kk < K; kk += 16) {
    float4 a = *(const float4*)(A + (size_t)(m0 + row) * K + kk + q * 4);
    float4 w = *(const float4*)(W + (size_t)(n0 + row) * K + kk + q * 4);
    As[(q * 4 + 0) * 68 + row] = a.x; As[(q * 4 + 1) * 68 + row] = a.y;
    As[(q * 4 + 2) * 68 + row] = a.z; As[(q * 4 + 3) * 68 + row] = a.w;
    Ws[(q * 4 + 0) * 68 + row] = w.x; Ws[(q * 4 + 1) * 68 + row] = w.y;
    Ws[(q * 4 + 2) * 68 + row] = w.z; Ws[(q * 4 + 3) * 68 + row] = w.w;
    __syncthreads();
#pragma unroll
    for (int kl = 0; kl < 16; ++kl) {
      const float4 av = *(const float4*)(As + kl * 68 + tm * 4);
      const float4 wv = *(const float4*)(Ws + kl * 68 + tn * 4);
      const float am[4] = {av.x, av.y, av.z, av.w};
      const float wm[4] = {wv.x, wv.y, wv.z, wv.w};
#pragma unroll
      for (int i = 0; i < 4; ++i)
#pragma unroll
        for (int j = 0; j < 4; ++j) acc[i][j] = fmaf(am[i], wm[j], acc[i][j]);
    }
    __syncthreads();
  }
  float4 bz = make_float4(0.f, 0.f, 0.f, 0.f);
  if (bias) bz = *(const float4*)(bias + n0 + tn * 4);
#pragma unroll
  for (int i = 0; i < 4; ++i) {
    float4 o = make_float4(acc[i][0] + bz.x, acc[i][1] + bz.y,
                           acc[i][2] + bz.z, acc[i][3] + bz.w);
    *(float4*)(C + (size_t)(m0 + tm * 4 + i) * ldC + n0 + tn * 4) = o;
  }
}

// ---------------- whh repack with XOR-swizzle for conflict-free b128 reads.
// out[((dir*8+sl)*128 + r)*256 + ((k4 ^ (r&63))*4 + ki)] = whh[dir][g][k]
//   r = gate*32 + j, g = gate*256 + sl*32 + j, k = k4*4 + ki
__global__ void prep_whh(const float* __restrict__ whh, float* __restrict__ out) {
  int idx = blockIdx.x * 256 + threadIdx.x;        // 2*8*128*256 = 524288
  int pos = idx & 255;
  int r = (idx >> 8) & 127;
  int sl = (idx >> 15) & 7;
  int dir = idx >> 18;
  int ki = pos & 3;
  int k4 = (pos >> 2) ^ (r & 63);
  int k = k4 * 4 + ki;
  int g = (r >> 5) * 256 + sl * 32 + (r & 31);
  out[idx] = whh[(size_t)(dir * GG + g) * HH + k];
}

// ---------------- LSTM recurrence (one layer, both dirs), one chain per wg.
// grid = 256: bid = (d + 2*bg) + 32*sl.  wg: slice sl (32 units), dir d, batches
// {2bg, 2bg+1}.  8-wg sync group (d,bg) shares bid%32 -> same bid%8 -> one XCD
// (perf heuristic only; protocol is agent-scope correct regardless).
// Sync: self-flagging 64-bit words (tag<<32 | float bits), relaxed agent-scope
// 8B atomics, double-buffered by t-parity.  1 store->visible hop per step.
// Poll is THROTTLED: one 4-load sweep per __syncthreads_and round + s_sleep
// backoff (avoids hammering the coherence point, which delays producer stores).
// hist (HBM) is written CONSUMER-side by the sl==0 wg from its polled registers
// (coalesced float4, issued early in the step -> HBM ack hidden under compute),
// keeping the producer epilogue's outstanding stores to a single 8B L3 atomic.
__launch_bounds__(128)
__global__ void rec_kernel(const float* __restrict__ Xp, const float* __restrict__ whh_p,
                           float* __restrict__ hist, u64* __restrict__ hx) {
  __shared__ float whh_lds[32768];   // [r*256 + swz(k)], 128KB
  __shared__ float h_lds[512];       // [c*256 + k]
  __shared__ float g_lds[256];       // [r*2 + c]
  const int tid = threadIdx.x;
  const int bid = blockIdx.x;
  const int sl = bid >> 5;
  const int db = bid & 31;
  const int d = db & 1;
  const int bg = db >> 1;
  const int r = tid;                 // gate row 0..127 (gate*32+j)
  const int swz = r & 63;
  const float* wp = whh_p + (size_t)(d * 8 + sl) * 32768;
  for (int i = tid * 4; i < 32768; i += 512)
    *(float4*)&whh_lds[i] = *(const float4*)&wp[i];
  const float* XpD = Xp + (size_t)d * MM * GG;
  const int gcol = (r >> 5) * 256 + sl * 32 + (r & 31);
  const int jj = tid & 31, cc = tid >> 5;        // producer epilogue mapping (tid<64)
  const int hc = tid >> 6, hk = (tid & 63) * 4;  // consumer word mapping: c*256+k = tid*4
  float creg = 0.f;                              // LSTM cell state (valid tid<64)
  // group base: hx[slot][d][bg][512]
  u64* grp[2] = { hx + ((size_t)(0 * 2 + d) * 16 + bg) * 512,
                  hx + ((size_t)(1 * 2 + d) * 16 + bg) * 512 };
  __syncthreads();   // whh_lds ready
  for (int t = 0; t < SS; ++t) {
    const int s = d ? (SS - 1 - t) : t;
    // xp loads issued before the poll: HBM latency hides under the spin
    const int m0 = s * BB + bg * 2;
    const float xp0 = XpD[(size_t)m0 * GG + gcol];
    const float xp1 = XpD[(size_t)(m0 + 1) * GG + gcol];
    // ---- throttled poll of this step's 512 tagged words ----
    u64 w0, w1, w2, w3;
    {
      u64* base = grp[t & 1] + tid * 4;
      for (;;) {
        w0 = __hip_atomic_load(base + 0, __ATOMIC_RELAXED, __HIP_MEMORY_SCOPE_AGENT);
        w1 = __hip_atomic_load(base + 1, __ATOMIC_RELAXED, __HIP_MEMORY_SCOPE_AGENT);
        w2 = __hip_atomic_load(base + 2, __ATOMIC_RELAXED, __HIP_MEMORY_SCOPE_AGENT);
        w3 = __hip_atomic_load(base + 3, __ATOMIC_RELAXED, __HIP_MEMORY_SCOPE_AGENT);
        int ready = ((u32)(w0 >> 32) == (u32)t) & ((u32)(w1 >> 32) == (u32)t) &
                    ((u32)(w2 >> 32) == (u32)t) & ((u32)(w3 >> 32) == (u32)t);
        if (__syncthreads_and(ready)) break;
        __builtin_amdgcn_s_sleep(2);
      }
    }
    *(float4*)&h_lds[tid * 4] = make_float4(
        __uint_as_float((u32)w0), __uint_as_float((u32)w1),
        __uint_as_float((u32)w2), __uint_as_float((u32)w3));
    // consumer-side hist write for step t-1 (h_{t-1} is what we just polled)
    if (sl == 0 && t > 0) {
      const int sp = d ? (SS - t) : (t - 1);
      *(float4*)&hist[(size_t)(sp * BB + bg * 2 + hc) * 512 + d * 256 + hk] =
          make_float4(__uint_as_float((u32)w0), __uint_as_float((u32)w1),
                      __uint_as_float((u32)w2), __uint_as_float((u32)w3));
    }
    __syncthreads();   // h_lds ready
    {
      float acc0 = 0.f, acc1 = 0.f;
#pragma unroll 8
      for (int k4 = 0; k4 < 64; ++k4) {
        const float4 w = *(const float4*)&whh_lds[r * 256 + ((k4 ^ swz) << 2)];
        const float4 h0 = *(const float4*)&h_lds[k4 * 4];
        const float4 h1 = *(const float4*)&h_lds[256 + k4 * 4];
        acc0 = fmaf(w.x, h0.x, acc0); acc0 = fmaf(w.y, h0.y, acc0);
        acc0 = fmaf(w.z, h0.z, acc0); acc0 = fmaf(w.w, h0.w, acc0);
        acc1 = fmaf(w.x, h1.x, acc1); acc1 = fmaf(w.y, h1.y, acc1);
        acc1 = fmaf(w.z, h1.z, acc1); acc1 = fmaf(w.w, h1.w, acc1);
      }
      *(float2*)&g_lds[r * 2] = make_float2(acc0 + xp0, acc1 + xp1);
    }
    __syncthreads();   // g_lds ready
    if (tid < 64) {    // producer epilogue: only a single 8B L3 atomic outstanding
      const float iv = g_lds[(jj) * 2 + cc];
      const float fv = g_lds[(32 + jj) * 2 + cc];
      const float gv = g_lds[(64 + jj) * 2 + cc];
      const float ov = g_lds[(96 + jj) * 2 + cc];
      const float cs = sigm(fv) * creg + sigm(iv) * tanhf(gv);
      creg = cs;
      const float hn = sigm(ov) * tanhf(cs);
      u64 w = ((u64)(u32)(t + 1) << 32) | (u64)__float_as_uint(hn);
      __hip_atomic_store(grp[(t + 1) & 1] + cc * 256 + sl * 32 + jj, w,
                         __ATOMIC_RELAXED, __HIP_MEMORY_SCOPE_AGENT);
    }
  }
  // flush the final h (tag SS, produced at end of t=SS-1) to hist — sl==0 wgs only
  if (sl == 0) {
    u64* base = grp[SS & 1] + tid * 4;
    u64 w0, w1, w2, w3;
    for (;;) {
      w0 = __hip_atomic_load(base + 0, __ATOMIC_RELAXED, __HIP_MEMORY_SCOPE_AGENT);
      w1 = __hip_atomic_load(base + 1, __ATOMIC_RELAXED, __HIP_MEMORY_SCOPE_AGENT);
      w2 = __hip_atomic_load(base + 2, __ATOMIC_RELAXED, __HIP_MEMORY_SCOPE_AGENT);
      w3 = __hip_atomic_load(base + 3, __ATOMIC_RELAXED, __HIP_MEMORY_SCOPE_AGENT);
      int ready = ((u32)(w0 >> 32) == (u32)SS) & ((u32)(w1 >> 32) == (u32)SS) &
                  ((u32)(w2 >> 32) == (u32)SS) & ((u32)(w3 >> 32) == (u32)SS);
      if (__syncthreads_and(ready)) break;
      __builtin_amdgcn_s_sleep(2);
    }
    const int sp = d ? 0 : (SS - 1);
    *(float4*)&hist[(size_t)(sp * BB + bg * 2 + hc) * 512 + d * 256 + hk] =
        make_float4(__uint_as_float((u32)w0), __uint_as_float((u32)w1),
                    __uint_as_float((u32)w2), __uint_as_float((u32)w3));
  }
}

// ---------------- attention: scores over NS=16 sentence embs, softmax, g; writes comb[512:1024]
__global__ void att_kernel(float* __restrict__ comb, const float* __restrict__ sent) {
  __shared__ float sl[NSENT * 512];   // 32 KB
  __shared__ float wxr[512];
  __shared__ float parts[256];
  __shared__ float aw[NSENT];
  __shared__ float red0;
  const int tid = threadIdx.x;
  const int b = blockIdx.y;
  const int s0 = blockIdx.x * 32;
  for (int i = tid; i < NSENT * 512; i += 256) sl[i] = sent[(size_t)b * NSENT * 512 + i];
  __syncthreads();
  for (int si = 0; si < 32; ++si) {
    const int m = (s0 + si) * BB + b;
    float* crow = comb + (size_t)m * 1024;
    for (int i = tid; i < 512; i += 256) wxr[i] = crow[i];
    __syncthreads();
    const int n = tid >> 4, kp = tid & 15;
    float p = 0.f;
#pragma unroll 8
    for (int f = kp * 32; f < kp * 32 + 32; ++f) p = fmaf(wxr[f], sl[n * 512 + f], p);
    parts[tid] = p;
    __syncthreads();
    if (tid < NSENT) {
      float sc = 0.f;
      for (int qq = 0; qq < 16; ++qq) sc += parts[tid * 16 + qq];
      aw[tid] = sc;
    }
    __syncthreads();
    if (tid == 0) {
      float mx = aw[0];
      for (int qq = 1; qq < NSENT; ++qq) mx = fmaxf(mx, aw[qq]);
      float sm = 0.f;
      for (int qq = 0; qq < NSENT; ++qq) { float e = expf(aw[qq] - mx); aw[qq] = e; sm += e; }
      red0 = 1.f / sm;
    }
    __syncthreads();
    const float inv = red0;
    for (int f = tid; f < 512; f += 256) {
      float g = 0.f;
#pragma unroll
      for (int qq = 0; qq < NSENT; ++qq) g = fmaf(aw[qq], sl[qq * 512 + f], g);
      crow[512 + f] = g * inv;
    }
    __syncthreads();
  }
}

// ---------------- feats[m][t] = l2m[m][:] . h2t_w[t][:] + h2t_b[t]; wave per row
__global__ void feats_kernel(const float* __restrict__ l2m, const float* __restrict__ w,
                             const float* __restrict__ bias, float* __restrict__ feats) {
  const int wave = threadIdx.x >> 6, lane = threadIdx.x & 63;
  const int m = blockIdx.x * 4 + wave;
  const float* row = l2m + (size_t)m * 512;
  float rv[8];
#pragma unroll
  for (int i = 0; i < 8; ++i) rv[i] = row[lane + i * 64];
  for (int t = 0; t < TT; ++t) {
    const float* wr = w + t * 512;
    float p = 0.f;
#pragma unroll
    for (int i = 0; i < 8; ++i) p = fmaf(rv[i], wr[lane + i * 64], p);
#pragma unroll
    for (int off = 32; off; off >>= 1) p += __shfl_down(p, off);
    if (lane == 0) feats[(size_t)m * TT + t] = p + bias[t];
  }
}

// ---------------- viterbi per batch; 1 wave, whole DP in LDS
__global__ void viterbi_kernel(const float* __restrict__ feats, const float* __restrict__ trans,
                               int* __restrict__ out) {
  __shared__ float flds[SS * TT];
  __shared__ unsigned char bp[SS * TT];
  __shared__ float tr[TT * TT];
  __shared__ float fv[TT];
  __shared__ float tv[TT];
  __shared__ int pathS[SS];
  const int b = blockIdx.x, tid = threadIdx.x;
  for (int i = tid; i < SS * TT; i += 64) {
    int s = i / TT, t = i - s * TT;
    flds[i] = feats[(size_t)(s * BB + b) * TT + t];
  }
  for (int i = tid; i < TT * TT; i += 64) tr[i] = trans[i];
  if (tid < TT) fv[tid] = (tid == TAG_START) ? 0.f : -10000.f;
  __syncthreads();
  for (int s = 0; s < SS; ++s) {
    float nf = 0.f;
    if (tid < TT) {
      float mx = -1e30f;
      int bj = 0;
#pragma unroll
      for (int jj = 0; jj < TT; ++jj) {
        float v = fv[jj] + tr[tid * TT + jj];
        if (v > mx) { mx = v; bj = jj; }
      }
      nf = mx + flds[s * TT + tid];
      bp[s * TT + tid] = (unsigned char)bj;
    }
    __syncthreads();
    if (tid < TT) fv[tid] = nf;
    __syncthreads();
  }
  if (tid < TT) tv[tid] = fv[tid] + tr[TAG_STOP * TT + tid];
  __syncthreads();
  if (tid == 0) {
    int best = 0;
    float mx = tv[0];
    for (int jj = 1; jj < TT; ++jj)
      if (tv[jj] > mx) { mx = tv[jj]; best = jj; }
    pathS[SS - 1] = best;
    for (int s = SS - 1; s > 0; --s) { best = bp[s * TT + best]; pathS[s - 1] = best; }
  }
  __syncthreads();
  for (int s = tid; s < SS; s += 64) out[b * SS + s] = pathS[s];
}

// ---------------- workspace layout (bytes) — total ~240.4 MB < 256 MB ----------------
#define OFF_XP    ((size_t)0)               // 2*16384*1024*4 = 134217728
#define OFF_COMB  ((size_t)134217728)       // 16384*1024*4 = 67108864 (X1 and l2m alias here)
#define OFF_WORD  ((size_t)201326592)       // 16384*512*4  = 33554432
#define OFF_WT1   ((size_t)234881024)       // 2097152
#define OFF_WT2   ((size_t)236978176)       // 2097152
#define OFF_FEATS ((size_t)239075328)       // 786432
#define OFF_HX1   ((size_t)239861760)       // 262144  (2 slots * 2 dir * 16 g * 512 u64)
#define OFF_HX2   ((size_t)240123904)       // 262144

extern "C" void kernel_launch(void* const* d_in, const int* in_sizes, int n_in,
                              void* d_out, int out_size, void* d_ws, size_t ws_size,
                              hipStream_t stream) {
  const int* inputs  = (const int*)d_in[0];
  const float* sent  = (const float*)d_in[1];
  const float* emb   = (const float*)d_in[2];
  const float* l1wih = (const float*)d_in[3];
  const float* l1whh = (const float*)d_in[4];
  const float* l1b   = (const float*)d_in[5];
  const float* l2wih = (const float*)d_in[6];
  const float* l2whh = (const float*)d_in[7];
  const float* l2b   = (const float*)d_in[8];
  const float* attW  = (const float*)d_in[9];
  const float* h2tw  = (const float*)d_in[10];
  const float* h2tb  = (const float*)d_in[11];
  const float* trans = (const float*)d_in[12];
  int* out = (int*)d_out;
  char* ws = (char*)d_ws;

  float* Xp    = (float*)(ws + OFF_XP);
  float* comb  = (float*)(ws + OFF_COMB);
  float* word  = (float*)(ws + OFF_WORD);
  float* X1    = comb;   // X1 dead before comb is written (wx GEMM reads word only)
  float* l2m   = comb;   // comb dead before rec2 writes l2m
  float* wt1   = (float*)(ws + OFF_WT1);
  float* wt2   = (float*)(ws + OFF_WT2);
  float* feats = (float*)(ws + OFF_FEATS);
  u64* hx1     = (u64*)(ws + OFF_HX1);
  u64* hx2     = (u64*)(ws + OFF_HX2);

  // zero both tagged-h buffers (contiguous 512 KB): tag 0 == "h_{-1}=0 ready"
  hipMemsetAsync(ws + OFF_HX1, 0, 262144 * 2, stream);

  prep_whh<<<2048, 256, 0, stream>>>(l1whh, wt1);
  prep_whh<<<2048, 256, 0, stream>>>(l2whh, wt2);
  embed_kernel<<<MM, 64, 0, stream>>>(inputs, emb, X1);
  for (int d = 0; d < 2; ++d)
    gemm_nt<<<dim3(16, 256), 256, 0, stream>>>(X1, l1wih + (size_t)d * GG * DD,
                                               l1b + d * GG, Xp + (size_t)d * MM * GG,
                                               DD, GG);
  rec_kernel<<<256, 128, 0, stream>>>(Xp, wt1, word, hx1);
  gemm_nt<<<dim3(8, 256), 256, 0, stream>>>(word, attW, nullptr, comb, 512, 1024);
  att_kernel<<<dim3(16, 32), 256, 0, stream>>>(comb, sent);
  for (int d = 0; d < 2; ++d)
    gemm_nt<<<dim3(16, 256), 256, 0, stream>>>(comb, l2wih + (size_t)d * GG * GG,
                                               l2b + d * GG, Xp + (size_t)d * MM * GG,
                                               GG, GG);
  rec_kernel<<<256, 128, 0, stream>>>(Xp, wt2, l2m, hx2);
  feats_kernel<<<MM / 4, 256, 0, stream>>>(l2m, h2tw, h2tb, feats);
  viterbi_kernel<<<BB, 64, 0, stream>>>(feats, trans, out);
}

// Round 6
// 5401.390 us; speedup vs baseline: 1.6251x; 1.1331x over previous
//
#include <hip/hip_runtime.h>
#include <hip/hip_bf16.h>

// Problem constants
#define BB 32
#define SS 512
#define DD 256
#define HH 256
#define GG 1024          // 4*H
#define MM (SS*BB)       // 16384 rows, m = s*32 + b
#define NSENT 16
#define TT 12
#define TAG_START 10
#define TAG_STOP 11

typedef unsigned long long u64;
typedef unsigned int u32;

__device__ __forceinline__ float sigm(float x) {
  x = fminf(fmaxf(x, -15.f), 15.f);
  return 1.f / (1.f + __expf(-x));
}
__device__ __forceinline__ float tanh_fast(float x) {
  x = fminf(fmaxf(x, -15.f), 15.f);
  float e = __expf(2.f * x);
  return (e - 1.f) / (e + 1.f);
}

// ---------------- embed gather: X1[m][d] = embed[inputs[b][s]][d], m = s*32+b
__global__ void embed_kernel(const int* __restrict__ toks, const float* __restrict__ emb,
                             float* __restrict__ X1) {
  int m = blockIdx.x;
  int s = m >> 5, b = m & 31;
  int tok = toks[b * SS + s];
  ((float4*)(X1 + (size_t)m * DD))[threadIdx.x] =
      ((const float4*)(emb + (size_t)tok * DD))[threadIdx.x];
}

// ---------------- fp32 NT GEMM: C[M,N] = A[M,K] @ W[N,K]^T + bias, 64x64 tile
// LDS leading dim padded 64->68: staging writes 2-way max (free), b128 reads conflict-free.
__launch_bounds__(256)
__global__ void gemm_nt(const float* __restrict__ A, const float* __restrict__ W,
                        const float* __restrict__ bias, float* __restrict__ C,
                        int K, int ldC) {
  __shared__ float As[16 * 68];
  __shared__ float Ws[16 * 68];
  const int tid = threadIdx.x;
  const int n0 = blockIdx.x * 64, m0 = blockIdx.y * 64;
  const int row = tid >> 2, q = tid & 3;
  const int tn = tid & 15, tm = tid >> 4;
  float acc[4][4] = {};
  for (int kk = 0; kk < K; kk += 16) {
    float4 a = *(const float4*)(A + (size_t)(m0 + row) * K + kk + q * 4);
    float4 w = *(const float4*)(W + (size_t)(n0 + row) * K + kk + q * 4);
    As[(q * 4 + 0) * 68 + row] = a.x; As[(q * 4 + 1) * 68 + row] = a.y;
    As[(q * 4 + 2) * 68 + row] = a.z; As[(q * 4 + 3) * 68 + row] = a.w;
    Ws[(q * 4 + 0) * 68 + row] = w.x; Ws[(q * 4 + 1) * 68 + row] = w.y;
    Ws[(q * 4 + 2) * 68 + row] = w.z; Ws[(q * 4 + 3) * 68 + row] = w.w;
    __syncthreads();
#pragma unroll
    for (int kl = 0; kl < 16; ++kl) {
      const float4 av = *(const float4*)(As + kl * 68 + tm * 4);
      const float4 wv = *(const float4*)(Ws + kl * 68 + tn * 4);
      const float am[4] = {av.x, av.y, av.z, av.w};
      const float wm[4] = {wv.x, wv.y, wv.z, wv.w};
#pragma unroll
      for (int i = 0; i < 4; ++i)
#pragma unroll
        for (int j = 0; j < 4; ++j) acc[i][j] = fmaf(am[i], wm[j], acc[i][j]);
    }
    __syncthreads();
  }
  float4 bz = make_float4(0.f, 0.f, 0.f, 0.f);
  if (bias) bz = *(const float4*)(bias + n0 + tn * 4);
#pragma unroll
  for (int i = 0; i < 4; ++i) {
    float4 o = make_float4(acc[i][0] + bz.x, acc[i][1] + bz.y,
                           acc[i][2] + bz.z, acc[i][3] + bz.w);
    *(float4*)(C + (size_t)(m0 + tm * 4 + i) * ldC + n0 + tn * 4) = o;
  }
}

// ---------------- whh repack with XOR-swizzle for conflict-free b128 reads.
// out[((dir*8+sl)*128 + r)*256 + ((k4 ^ (r&63))*4 + ki)] = whh[dir][g][k]
//   r = gate*32 + j, g = gate*256 + sl*32 + j, k = k4*4 + ki
__global__ void prep_whh(const float* __restrict__ whh, float* __restrict__ out) {
  int idx = blockIdx.x * 256 + threadIdx.x;        // 2*8*128*256 = 524288
  int pos = idx & 255;
  int r = (idx >> 8) & 127;
  int sl = (idx >> 15) & 7;
  int dir = idx >> 18;
  int ki = pos & 3;
  int k4 = (pos >> 2) ^ (r & 63);
  int k = k4 * 4 + ki;
  int g = (r >> 5) * 256 + sl * 32 + (r & 31);
  out[idx] = whh[(size_t)(dir * GG + g) * HH + k];
}

// ---------------- LSTM recurrence (one layer, both dirs), one chain per wg.
// grid = 256: bid = (d + 2*bg) + 32*sl.  wg: slice sl (32 units), dir d, batches
// {2bg, 2bg+1}.  Sync: self-flagging 64-bit words (tag<<32 | float bits), relaxed
// agent-scope 8B atomics, double-buffered by t-parity.  1 store->visible hop/step.
// Poll is PER-THREAD and BARRIER-FREE: each thread spins only on its own 4 words
// and stages them into h_lds the moment they arrive; exactly 2 barriers/step.
// (Slot-parity WAR chain makes tag t+1 unable to appear before every wg finished
// its step-t h_lds reads, so early stagers can't race laggards' compute.)
// hist (HBM) is written consumer-side by the sl==0 wg from polled registers.
__launch_bounds__(128)
__global__ void rec_kernel(const float* __restrict__ Xp, const float* __restrict__ whh_p,
                           float* __restrict__ hist, u64* __restrict__ hx) {
  __shared__ float whh_lds[32768];   // [r*256 + swz(k)], 128KB
  __shared__ float h_lds[512];       // [c*256 + k]
  __shared__ float g_lds[256];       // [r*2 + c]
  const int tid = threadIdx.x;
  const int bid = blockIdx.x;
  const int sl = bid >> 5;
  const int db = bid & 31;
  const int d = db & 1;
  const int bg = db >> 1;
  const int r = tid;                 // gate row 0..127 (gate*32+j)
  const int swz = r & 63;
  const float* wp = whh_p + (size_t)(d * 8 + sl) * 32768;
  for (int i = tid * 4; i < 32768; i += 512)
    *(float4*)&whh_lds[i] = *(const float4*)&wp[i];
  const float* XpD = Xp + (size_t)d * MM * GG;
  const int gcol = (r >> 5) * 256 + sl * 32 + (r & 31);
  const int jj = tid & 31, cc = tid >> 5;        // producer epilogue mapping (tid<64)
  const int hc = tid >> 6, hk = (tid & 63) * 4;  // consumer word mapping: c*256+k = tid*4
  float creg = 0.f;                              // LSTM cell state (valid tid<64)
  // group base: hx[slot][d][bg][512]
  u64* grp[2] = { hx + ((size_t)(0 * 2 + d) * 16 + bg) * 512,
                  hx + ((size_t)(1 * 2 + d) * 16 + bg) * 512 };
  __syncthreads();   // whh_lds ready
  for (int t = 0; t < SS; ++t) {
    const int s = d ? (SS - 1 - t) : t;
    // xp loads issued before the spin: HBM latency hides under it
    const int m0 = s * BB + bg * 2;
    const float xp0 = XpD[(size_t)m0 * GG + gcol];
    const float xp1 = XpD[(size_t)(m0 + 1) * GG + gcol];
    // ---- per-thread barrier-free spin on my 4 tagged words ----
    u64 w0, w1, w2, w3;
    {
      u64* base = grp[t & 1] + tid * 4;
      w0 = __hip_atomic_load(base + 0, __ATOMIC_RELAXED, __HIP_MEMORY_SCOPE_AGENT);
      w1 = __hip_atomic_load(base + 1, __ATOMIC_RELAXED, __HIP_MEMORY_SCOPE_AGENT);
      w2 = __hip_atomic_load(base + 2, __ATOMIC_RELAXED, __HIP_MEMORY_SCOPE_AGENT);
      w3 = __hip_atomic_load(base + 3, __ATOMIC_RELAXED, __HIP_MEMORY_SCOPE_AGENT);
      while (((u32)(w0 >> 32) != (u32)t) | ((u32)(w1 >> 32) != (u32)t) |
             ((u32)(w2 >> 32) != (u32)t) | ((u32)(w3 >> 32) != (u32)t)) {
        __builtin_amdgcn_s_sleep(1);
        w0 = __hip_atomic_load(base + 0, __ATOMIC_RELAXED, __HIP_MEMORY_SCOPE_AGENT);
        w1 = __hip_atomic_load(base + 1, __ATOMIC_RELAXED, __HIP_MEMORY_SCOPE_AGENT);
        w2 = __hip_atomic_load(base + 2, __ATOMIC_RELAXED, __HIP_MEMORY_SCOPE_AGENT);
        w3 = __hip_atomic_load(base + 3, __ATOMIC_RELAXED, __HIP_MEMORY_SCOPE_AGENT);
      }
    }
    *(float4*)&h_lds[tid * 4] = make_float4(
        __uint_as_float((u32)w0), __uint_as_float((u32)w1),
        __uint_as_float((u32)w2), __uint_as_float((u32)w3));
    // consumer-side hist write for step t-1 (h_{t-1} is what we just polled)
    if (sl == 0 && t > 0) {
      const int sp = d ? (SS - t) : (t - 1);
      *(float4*)&hist[(size_t)(sp * BB + bg * 2 + hc) * 512 + d * 256 + hk] =
          make_float4(__uint_as_float((u32)w0), __uint_as_float((u32)w1),
                      __uint_as_float((u32)w2), __uint_as_float((u32)w3));
    }
    __syncthreads();   // (b) h_lds complete
    {
      float acc0 = 0.f, acc1 = 0.f;
#pragma unroll 8
      for (int k4 = 0; k4 < 64; ++k4) {
        const float4 w = *(const float4*)&whh_lds[r * 256 + ((k4 ^ swz) << 2)];
        const float4 h0 = *(const float4*)&h_lds[k4 * 4];
        const float4 h1 = *(const float4*)&h_lds[256 + k4 * 4];
        acc0 = fmaf(w.x, h0.x, acc0); acc0 = fmaf(w.y, h0.y, acc0);
        acc0 = fmaf(w.z, h0.z, acc0); acc0 = fmaf(w.w, h0.w, acc0);
        acc1 = fmaf(w.x, h1.x, acc1); acc1 = fmaf(w.y, h1.y, acc1);
        acc1 = fmaf(w.z, h1.z, acc1); acc1 = fmaf(w.w, h1.w, acc1);
      }
      *(float2*)&g_lds[r * 2] = make_float2(acc0 + xp0, acc1 + xp1);
    }
    __syncthreads();   // (c) g_lds ready; also fences h_lds reads vs next-step writes
    if (tid < 64) {    // producer epilogue: single 8B L3 atomic on the critical path
      const float iv = g_lds[(jj) * 2 + cc];
      const float fv = g_lds[(32 + jj) * 2 + cc];
      const float gv = g_lds[(64 + jj) * 2 + cc];
      const float ov = g_lds[(96 + jj) * 2 + cc];
      const float cs = sigm(fv) * creg + sigm(iv) * tanh_fast(gv);
      creg = cs;
      const float hn = sigm(ov) * tanh_fast(cs);
      u64 w = ((u64)(u32)(t + 1) << 32) | (u64)__float_as_uint(hn);
      __hip_atomic_store(grp[(t + 1) & 1] + cc * 256 + sl * 32 + jj, w,
                         __ATOMIC_RELAXED, __HIP_MEMORY_SCOPE_AGENT);
    }
  }
  // flush the final h (tag SS, produced at end of t=SS-1) to hist — sl==0 wgs only
  if (sl == 0) {
    u64* base = grp[SS & 1] + tid * 4;
    u64 w0, w1, w2, w3;
    do {
      w0 = __hip_atomic_load(base + 0, __ATOMIC_RELAXED, __HIP_MEMORY_SCOPE_AGENT);
      w1 = __hip_atomic_load(base + 1, __ATOMIC_RELAXED, __HIP_MEMORY_SCOPE_AGENT);
      w2 = __hip_atomic_load(base + 2, __ATOMIC_RELAXED, __HIP_MEMORY_SCOPE_AGENT);
      w3 = __hip_atomic_load(base + 3, __ATOMIC_RELAXED, __HIP_MEMORY_SCOPE_AGENT);
      if (((u32)(w0 >> 32) == (u32)SS) & ((u32)(w1 >> 32) == (u32)SS) &
          ((u32)(w2 >> 32) == (u32)SS) & ((u32)(w3 >> 32) == (u32)SS)) break;
      __builtin_amdgcn_s_sleep(1);
    } while (true);
    const int sp = d ? 0 : (SS - 1);
    *(float4*)&hist[(size_t)(sp * BB + bg * 2 + hc) * 512 + d * 256 + hk] =
        make_float4(__uint_as_float((u32)w0), __uint_as_float((u32)w1),
                    __uint_as_float((u32)w2), __uint_as_float((u32)w3));
  }
}

// ---------------- attention: scores over NS=16 sentence embs, softmax, g; writes comb[512:1024]
__global__ void att_kernel(float* __restrict__ comb, const float* __restrict__ sent) {
  __shared__ float sl[NSENT * 512];   // 32 KB
  __shared__ float wxr[512];
  __shared__ float parts[256];
  __shared__ float aw[NSENT];
  __shared__ float red0;
  const int tid = threadIdx.x;
  const int b = blockIdx.y;
  const int s0 = blockIdx.x * 32;
  for (int i = tid; i < NSENT * 512; i += 256) sl[i] = sent[(size_t)b * NSENT * 512 + i];
  __syncthreads();
  for (int si = 0; si < 32; ++si) {
    const int m = (s0 + si) * BB + b;
    float* crow = comb + (size_t)m * 1024;
    for (int i = tid; i < 512; i += 256) wxr[i] = crow[i];
    __syncthreads();
    const int n = tid >> 4, kp = tid & 15;
    float p = 0.f;
#pragma unroll 8
    for (int f = kp * 32; f < kp * 32 + 32; ++f) p = fmaf(wxr[f], sl[n * 512 + f], p);
    parts[tid] = p;
    __syncthreads();
    if (tid < NSENT) {
      float sc = 0.f;
      for (int qq = 0; qq < 16; ++qq) sc += parts[tid * 16 + qq];
      aw[tid] = sc;
    }
    __syncthreads();
    if (tid == 0) {
      float mx = aw[0];
      for (int qq = 1; qq < NSENT; ++qq) mx = fmaxf(mx, aw[qq]);
      float sm = 0.f;
      for (int qq = 0; qq < NSENT; ++qq) { float e = expf(aw[qq] - mx); aw[qq] = e; sm += e; }
      red0 = 1.f / sm;
    }
    __syncthreads();
    const float inv = red0;
    for (int f = tid; f < 512; f += 256) {
      float g = 0.f;
#pragma unroll
      for (int qq = 0; qq < NSENT; ++qq) g = fmaf(aw[qq], sl[qq * 512 + f], g);
      crow[512 + f] = g * inv;
    }
    __syncthreads();
  }
}

// ---------------- feats[m][t] = l2m[m][:] . h2t_w[t][:] + h2t_b[t]; wave per row
__global__ void feats_kernel(const float* __restrict__ l2m, const float* __restrict__ w,
                             const float* __restrict__ bias, float* __restrict__ feats) {
  const int wave = threadIdx.x >> 6, lane = threadIdx.x & 63;
  const int m = blockIdx.x * 4 + wave;
  const float* row = l2m + (size_t)m * 512;
  float rv[8];
#pragma unroll
  for (int i = 0; i < 8; ++i) rv[i] = row[lane + i * 64];
  for (int t = 0; t < TT; ++t) {
    const float* wr = w + t * 512;
    float p = 0.f;
#pragma unroll
    for (int i = 0; i < 8; ++i) p = fmaf(rv[i], wr[lane + i * 64], p);
#pragma unroll
    for (int off = 32; off; off >>= 1) p += __shfl_down(p, off);
    if (lane == 0) feats[(size_t)m * TT + t] = p + bias[t];
  }
}

// ---------------- viterbi per batch; 1 wave, whole DP in LDS
__global__ void viterbi_kernel(const float* __restrict__ feats, const float* __restrict__ trans,
                               int* __restrict__ out) {
  __shared__ float flds[SS * TT];
  __shared__ unsigned char bp[SS * TT];
  __shared__ float tr[TT * TT];
  __shared__ float fv[TT];
  __shared__ float tv[TT];
  __shared__ int pathS[SS];
  const int b = blockIdx.x, tid = threadIdx.x;
  for (int i = tid; i < SS * TT; i += 64) {
    int s = i / TT, t = i - s * TT;
    flds[i] = feats[(size_t)(s * BB + b) * TT + t];
  }
  for (int i = tid; i < TT * TT; i += 64) tr[i] = trans[i];
  if (tid < TT) fv[tid] = (tid == TAG_START) ? 0.f : -10000.f;
  __syncthreads();
  for (int s = 0; s < SS; ++s) {
    float nf = 0.f;
    if (tid < TT) {
      float mx = -1e30f;
      int bj = 0;
#pragma unroll
      for (int jj = 0; jj < TT; ++jj) {
        float v = fv[jj] + tr[tid * TT + jj];
        if (v > mx) { mx = v; bj = jj; }
      }
      nf = mx + flds[s * TT + tid];
      bp[s * TT + tid] = (unsigned char)bj;
    }
    __syncthreads();
    if (tid < TT) fv[tid] = nf;
    __syncthreads();
  }
  if (tid < TT) tv[tid] = fv[tid] + tr[TAG_STOP * TT + tid];
  __syncthreads();
  if (tid == 0) {
    int best = 0;
    float mx = tv[0];
    for (int jj = 1; jj < TT; ++jj)
      if (tv[jj] > mx) { mx = tv[jj]; best = jj; }
    pathS[SS - 1] = best;
    for (int s = SS - 1; s > 0; --s) { best = bp[s * TT + best]; pathS[s - 1] = best; }
  }
  __syncthreads();
  for (int s = tid; s < SS; s += 64) out[b * SS + s] = pathS[s];
}

// ---------------- workspace layout (bytes) — total ~240.4 MB < 256 MB ----------------
#define OFF_XP    ((size_t)0)               // 2*16384*1024*4 = 134217728
#define OFF_COMB  ((size_t)134217728)       // 16384*1024*4 = 67108864 (X1 and l2m alias here)
#define OFF_WORD  ((size_t)201326592)       // 16384*512*4  = 33554432
#define OFF_WT1   ((size_t)234881024)       // 2097152
#define OFF_WT2   ((size_t)236978176)       // 2097152
#define OFF_FEATS ((size_t)239075328)       // 786432
#define OFF_HX1   ((size_t)239861760)       // 262144  (2 slots * 2 dir * 16 g * 512 u64)
#define OFF_HX2   ((size_t)240123904)       // 262144

extern "C" void kernel_launch(void* const* d_in, const int* in_sizes, int n_in,
                              void* d_out, int out_size, void* d_ws, size_t ws_size,
                              hipStream_t stream) {
  const int* inputs  = (const int*)d_in[0];
  const float* sent  = (const float*)d_in[1];
  const float* emb   = (const float*)d_in[2];
  const float* l1wih = (const float*)d_in[3];
  const float* l1whh = (const float*)d_in[4];
  const float* l1b   = (const float*)d_in[5];
  const float* l2wih = (const float*)d_in[6];
  const float* l2whh = (const float*)d_in[7];
  const float* l2b   = (const float*)d_in[8];
  const float* attW  = (const float*)d_in[9];
  const float* h2tw  = (const float*)d_in[10];
  const float* h2tb  = (const float*)d_in[11];
  const float* trans = (const float*)d_in[12];
  int* out = (int*)d_out;
  char* ws = (char*)d_ws;

  float* Xp    = (float*)(ws + OFF_XP);
  float* comb  = (float*)(ws + OFF_COMB);
  float* word  = (float*)(ws + OFF_WORD);
  float* X1    = comb;   // X1 dead before comb is written (wx GEMM reads word only)
  float* l2m   = comb;   // comb dead before rec2 writes l2m
  float* wt1   = (float*)(ws + OFF_WT1);
  float* wt2   = (float*)(ws + OFF_WT2);
  float* feats = (float*)(ws + OFF_FEATS);
  u64* hx1     = (u64*)(ws + OFF_HX1);
  u64* hx2     = (u64*)(ws + OFF_HX2);

  // zero both tagged-h buffers (contiguous 512 KB): tag 0 == "h_{-1}=0 ready"
  hipMemsetAsync(ws + OFF_HX1, 0, 262144 * 2, stream);

  prep_whh<<<2048, 256, 0, stream>>>(l1whh, wt1);
  prep_whh<<<2048, 256, 0, stream>>>(l2whh, wt2);
  embed_kernel<<<MM, 64, 0, stream>>>(inputs, emb, X1);
  for (int d = 0; d < 2; ++d)
    gemm_nt<<<dim3(16, 256), 256, 0, stream>>>(X1, l1wih + (size_t)d * GG * DD,
                                               l1b + d * GG, Xp + (size_t)d * MM * GG,
                                               DD, GG);
  rec_kernel<<<256, 128, 0, stream>>>(Xp, wt1, word, hx1);
  gemm_nt<<<dim3(8, 256), 256, 0, stream>>>(word, attW, nullptr, comb, 512, 1024);
  att_kernel<<<dim3(16, 32), 256, 0, stream>>>(comb, sent);
  for (int d = 0; d < 2; ++d)
    gemm_nt<<<dim3(16, 256), 256, 0, stream>>>(comb, l2wih + (size_t)d * GG * GG,
                                               l2b + d * GG, Xp + (size_t)d * MM * GG,
                                               GG, GG);
  rec_kernel<<<256, 128, 0, stream>>>(Xp, wt2, l2m, hx2);
  feats_kernel<<<MM / 4, 256, 0, stream>>>(l2m, h2tw, h2tb, feats);
  viterbi_kernel<<<BB, 64, 0, stream>>>(feats, trans, out);
}